// Round 6
// baseline (168.372 us; speedup 1.0000x reference)
//
#include <hip/hip_runtime.h>
#include <hip/hip_fp16.h>

// MinGRU single-pass fused pipeline, round 13. Rounds 8-12 showed the GEMM
// pinned at 40-45us under every staging variant whose VMEM is issued right
// before the barrier that drains it; fixes that issued early either spilled
// (r9: +32 VGPR at the 128 cap), lost residency (r11: 3/CU), or lost
// coalescing (r12: scattered direct-global frags, 74us). This round issues
// early at ZERO register and ZERO occupancy cost:
//  - X staged as RAW FP32 via global_load_lds (no reg round-trip, no
//    ds_write, no cvt at stage; cvt_pk_bf16 happens at fragment read).
//  - BK=32 with double-buffered X LDS: 2 x 16KB = 32KB <= 36KB epilogue
//    overlay => LDS stays 36096 => 4 blocks/CU preserved.
//  - W fragments direct-to-register, double-buffered (32 VGPR; W is 256KB
//    L2-hot shared by all blocks - the part of r12 that worked).
//  - Per iter: {issue next X DMA + next W loads} -> ds_read fp32 frags ->
//    cvt -> 16 MFMA -> ONE barrier. The barrier's vmcnt(0) drains VMEM
//    issued a full phase earlier (issue-early/drain-late, T3/T4-lite).
// X LDS swizzle: row = 8 x 16B blocks (4 floats), global block b of row r
// at slot b ^ (r&7); per-slot bank load is exactly uniform for the frag
// read pattern (8 lanes per slot column, 32B/bank). DMA geometry identical
// to the proven bf16 path (srow=lane>>3, slot=lane&7, fetch slot^srow).
// Epilogue/scan/lookback/out + XCD co-location decode: byte-identical.

namespace {
constexpr int kB  = 8;
constexpr int kT  = 4096;
constexpr int kD  = 256;
constexpr int kH  = 256;

constexpr int TM  = 128;          // time rows per block
constexpr int TH  = 64;           // h cols per block (dual-W => 128 eff. N)
constexpr int kNT = kT / TM;      // 32 time-tiles per chain
constexpr int kNChain = kB * (kH / TH);   // 32 chains
constexpr int EPS = 66;           // epilogue LDS row stride (half)
} // namespace

typedef short s16x8 __attribute__((ext_vector_type(8)));
typedef short s16x4 __attribute__((ext_vector_type(4)));
typedef float f32x4 __attribute__((ext_vector_type(4)));

__device__ __forceinline__ short f2bf(float f) {
    union { float f; unsigned int u; } v; v.f = f;
    unsigned int r = v.u + 0x7fffu + ((v.u >> 16) & 1u);   // RNE
    return (short)(r >> 16);
}

// packed RNE f32x2 -> bf16x2 (low word = lo operand); same rounding as f2bf
__device__ __forceinline__ unsigned int cvt_pk_bf16(float lo, float hi) {
    unsigned int r;
    asm("v_cvt_pk_bf16_f32 %0, %1, %2" : "=v"(r) : "v"(lo), "v"(hi));
    return r;
}

__device__ __forceinline__ void load_lds16(const void* g, void* l) {
    __builtin_amdgcn_global_load_lds(
        (const __attribute__((address_space(1))) void*)g,
        (__attribute__((address_space(3))) void*)l, 16, 0, 0);
}

// ---------------------------------------------------------------------------
// Kernel 1 (tiny): fp32 -> bf16 for Wz, Wh; zero the 512 KB aggregate mailbox.
// ---------------------------------------------------------------------------
__global__ __launch_bounds__(256)
void prep(const float* __restrict__ Wz,
          const float* __restrict__ Wh,
          unsigned short* __restrict__ wzb,
          unsigned short* __restrict__ whb,
          float4* __restrict__ aggz)
{
    constexpr int W4 = kH * kD / 4;           // 16,384 each
    const int i = blockIdx.x * 256 + threadIdx.x;

    if (i >= 2 * W4) {                        // zero mailbox (32768 float4)
        float4 z; z.x = 0.f; z.y = 0.f; z.z = 0.f; z.w = 0.f;
        aggz[i - 2 * W4] = z;
        return;
    }
    const float* src; unsigned short* dst; int j;
    if (i < W4) { src = Wz; dst = wzb; j = i; }
    else        { src = Wh; dst = whb; j = i - W4; }
    const float4 v = ((const float4*)src)[j];
    s16x4 p;
    p[0] = f2bf(v.x); p[1] = f2bf(v.y); p[2] = f2bf(v.z); p[3] = f2bf(v.w);
    ((s16x4*)dst)[j] = p;
}

// ---------------------------------------------------------------------------
// Kernel 2: fp32-DMA double-buffered GEMM + sigmoid + block aggregate +
// lookback + apply + out. Grid: 1024 blocks (XCD-swizzled 1-D), 4 waves,
// 4 blocks/CU (all resident).
// ---------------------------------------------------------------------------
__global__ __launch_bounds__(256, 4)
void gemm_scan_fused(const float* __restrict__ x,
                     const unsigned short* __restrict__ wzb,
                     const unsigned short* __restrict__ whb,
                     const float* __restrict__ bz,
                     const float* __restrict__ bh,
                     const float* __restrict__ h0,
                     unsigned long long* __restrict__ agg,  // [32 chains][32 t][64 h]
                     float* __restrict__ out)
{
    // LDS: staging Xf[2][128][32] fp32 (2x16KB, XOR-swizzled 16B blocks),
    // overlaid after the K loop by a_lds/b_lds [128][66] half (33792 B);
    // + sub_lds[4][64] float2 @33792 ; + hs_lds[64] @35840. Total 36096 B.
    __shared__ __align__(16) unsigned char smem[36096];
    __half* a_lds   = (__half*)smem;                 // [128][EPS]
    __half* b_lds   = a_lds + 128 * EPS;
    float2* sub_lds = (float2*)(smem + 33792);       // [4][64]
    float*  hs_lds  = (float*)(smem + 35840);        // [64]

    const int tid  = threadIdx.x;
    const int lane = tid & 63;
    const int wv   = tid >> 6;
    const int ln15 = lane & 15;
    const int quad = lane >> 4;
    const int wr0  = (wv & 1) * 64;
    const int wc0  = (wv >> 1) * 32;

    // XCD co-location decode: the 4 col-groups of one (b,t) share id%8
    // (=> same XCD, shared X tile in that XCD's L2). Bijective over 1024.
    const int id  = blockIdx.x;
    const int r8  = id & 7;
    const int q   = id >> 3;
    const int cg  = q & 3;                   // col-group 0..3
    const int bt  = (q >> 2) * 8 + r8;       // 0..255
    const int b   = bt >> 5;
    const int t   = bt & 31;                 // time-tile in chain
    const int chain = b * 4 + cg;            // 0..31
    const int col0  = cg * TH;
    const int row0  = b * kT + t * TM;       // global BT row of tile top

    // X DMA geometry: per wave-instr 8 rows x 8 slots of 16B (4 floats).
    // lane covers row seg*8 + (lane>>3), LDS slot (lane&7); fetched global
    // 16B block = slot ^ srow (since (abs row)&7 == srow).
    const int srow = lane >> 3;              // 0..7
    const int swslot = (lane & 7) ^ srow;    // swizzled global 16B block

    // W fragment bases (direct-to-reg, register double-buffered).
    const unsigned short* wzbase =
        wzb + (size_t)(col0 + wc0 + ln15) * kD + quad * 8;
    const unsigned short* whbase =
        whb + (size_t)(col0 + wc0 + ln15) * kD + quad * 8;

    f32x4 accZ[4][2] = {};
    f32x4 accU[4][2] = {};
    s16x8 wzr[2][2], whr[2][2];

    // ---- prologue: DMA X tile 0 into buf0; load W frags 0
    #pragma unroll
    for (int s2 = 0; s2 < 4; ++s2) {
        const int seg = wv * 4 + s2;                 // 0..15, rows seg*8..+8
        load_lds16(x + (size_t)(row0 + seg * 8 + srow) * kD + swslot * 4,
                   (float*)smem + seg * 256);
    }
    #pragma unroll
    for (int nt = 0; nt < 2; ++nt) {
        wzr[0][nt] = *(const s16x8*)(wzbase + (size_t)nt * 16 * kD);
        whr[0][nt] = *(const s16x8*)(whbase + (size_t)nt * 16 * kD);
    }
    __syncthreads();   // drains X DMA (vmcnt)

    // ---- K loop: 8 iters of K=32, one barrier each, issue-early/drain-late
    #pragma unroll
    for (int st = 0; st < 8; ++st) {
        const int cur = st & 1;
        if (st < 7) {
            const int o = (st + 1) * 32;
            const int nb = cur ^ 1;
            #pragma unroll
            for (int s2 = 0; s2 < 4; ++s2) {
                const int seg = wv * 4 + s2;
                load_lds16(
                    x + (size_t)(row0 + seg * 8 + srow) * kD + o + swslot * 4,
                    (float*)smem + nb * 4096 + seg * 256);
            }
            #pragma unroll
            for (int nt = 0; nt < 2; ++nt) {
                wzr[nb][nt] = *(const s16x8*)(wzbase + (size_t)nt * 16 * kD + o);
                whr[nb][nt] = *(const s16x8*)(whbase + (size_t)nt * 16 * kD + o);
            }
        }
        __builtin_amdgcn_sched_barrier(0);   // keep issues above the compute

        // fragment read (fp32, swizzled) + cvt -> bf16
        const float* Xc = (const float*)smem + cur * 4096;
        s16x8 af[4];
        #pragma unroll
        for (int mt = 0; mt < 4; ++mt) {
            const int r = wr0 + mt * 16 + ln15;
            const int m = r & 7;
            const int b0 = (2 * quad) ^ m;
            const int b1 = (2 * quad + 1) ^ m;
            const f32x4 f0 = *(const f32x4*)&Xc[(r << 5) + (b0 << 2)];
            const f32x4 f1 = *(const f32x4*)&Xc[(r << 5) + (b1 << 2)];
            union { unsigned int u[4]; s16x8 v; } pk;
            pk.u[0] = cvt_pk_bf16(f0[0], f0[1]);
            pk.u[1] = cvt_pk_bf16(f0[2], f0[3]);
            pk.u[2] = cvt_pk_bf16(f1[0], f1[1]);
            pk.u[3] = cvt_pk_bf16(f1[2], f1[3]);
            af[mt] = pk.v;
        }
        __builtin_amdgcn_s_setprio(1);
        #pragma unroll
        for (int mt = 0; mt < 4; ++mt) {
            #pragma unroll
            for (int nt = 0; nt < 2; ++nt) {
                accZ[mt][nt] = __builtin_amdgcn_mfma_f32_16x16x32_bf16(
                    af[mt], wzr[cur][nt], accZ[mt][nt], 0, 0, 0);
                accU[mt][nt] = __builtin_amdgcn_mfma_f32_16x16x32_bf16(
                    af[mt], whr[cur][nt], accU[mt][nt], 0, 0, 0);
            }
        }
        __builtin_amdgcn_s_setprio(0);
        __syncthreads();   // all waves done reading Xf[cur]; drains next DMA
    }

    // ---- epilogue: sigmoid; a/bb -> LDS fp16 (C/D: col=ln15, row=quad*4+r)
    #pragma unroll
    for (int nt = 0; nt < 2; ++nt) {
        const int col = col0 + wc0 + nt * 16 + ln15;
        const int lc  = wc0 + nt * 16 + ln15;
        const float bzv = bz[col];
        const float bhv = bh[col];
        #pragma unroll
        for (int mt = 0; mt < 4; ++mt) {
            const int rb = wr0 + mt * 16 + quad * 4;
            #pragma unroll
            for (int r = 0; r < 4; ++r) {
                const float z = accZ[mt][nt][r] + bzv;
                const float g = 1.0f / (1.0f + __expf(-z));
                const float u = accU[mt][nt][r] + bhv;
                a_lds[(rb + r) * EPS + lc] = __float2half_rn(1.0f - g);
                b_lds[(rb + r) * EPS + lc] = __float2half_rn(g * u);
            }
        }
    }
    __syncthreads();

    // ---- sub-chunk (32-row) affine summaries: thread (s,h)
    const int s = tid >> 6;
    const int h = tid & 63;
    {
        float A = 1.0f, Bv = 0.0f;
        #pragma unroll 8
        for (int r = s * 32; r < s * 32 + 32; ++r) {
            const float a  = __half2float(a_lds[r * EPS + h]);
            const float bb = __half2float(b_lds[r * EPS + h]);
            Bv = fmaf(a, Bv, bb);
            A *= a;
        }
        float2 o; o.x = A; o.y = Bv;
        sub_lds[s * 64 + h] = o;
    }
    __syncthreads();

    // ---- publish block aggregate + batched lookback (one lane per h)
    if (tid < 64) {
        float A = 1.0f, Bv = 0.0f;
        #pragma unroll
        for (int s2 = 0; s2 < 4; ++s2) {
            const float2 g = sub_lds[s2 * 64 + tid];
            Bv = fmaf(g.x, Bv, g.y);
            A *= g.x;
        }
        union { float2 f; unsigned long long u; } pk;
        pk.f.x = A; pk.f.y = Bv;
        pk.u |= 1ull;                         // never 0 => unambiguous ready flag
        __hip_atomic_store(&agg[(size_t)(chain * kNT + t) * 64 + tid], pk.u,
                           __ATOMIC_RELAXED, __HIP_MEMORY_SCOPE_AGENT);

        // lookback over predecessors 0..t-1, 8 at a time (independent loads,
        // one L2/L3 latency per batch; fold strictly in order).
        float hs = h0[(size_t)b * kH + col0 + tid];
        for (int j0 = 0; j0 < t; j0 += 8) {
            const int nb = (t - j0 < 8) ? (t - j0) : 8;
            unsigned long long u[8];
            #pragma unroll
            for (int q2 = 0; q2 < 8; ++q2)
                if (q2 < nb)
                    u[q2] = __hip_atomic_load(
                        &agg[(size_t)(chain * kNT + j0 + q2) * 64 + tid],
                        __ATOMIC_RELAXED, __HIP_MEMORY_SCOPE_AGENT);
            #pragma unroll
            for (int q2 = 0; q2 < 8; ++q2) {
                if (q2 < nb) {
                    while (u[q2] == 0ull)
                        u[q2] = __hip_atomic_load(
                            &agg[(size_t)(chain * kNT + j0 + q2) * 64 + tid],
                            __ATOMIC_RELAXED, __HIP_MEMORY_SCOPE_AGENT);
                    union { unsigned long long u; float2 f; } qk; qk.u = u[q2];
                    hs = fmaf(qk.f.x, hs, qk.f.y);
                }
            }
        }
        hs_lds[tid] = hs;
    }
    __syncthreads();

    // ---- apply recurrence: thread (s,h) does its 32 rows, writes out
    {
        float hv = hs_lds[h];
        #pragma unroll
        for (int s2 = 0; s2 < s; ++s2) {
            const float2 g = sub_lds[s2 * 64 + h];
            hv = fmaf(g.x, hv, g.y);
        }
        #pragma unroll 8
        for (int r = 0; r < 32; ++r) {
            const int lr = s * 32 + r;
            const float a  = __half2float(a_lds[lr * EPS + h]);
            const float bb = __half2float(b_lds[lr * EPS + h]);
            hv = fmaf(a, hv, bb);
            __builtin_nontemporal_store(hv, &out[(size_t)(row0 + lr) * kH + col0 + h]);
        }
    }
}

extern "C" void kernel_launch(void* const* d_in, const int* in_sizes, int n_in,
                              void* d_out, int out_size, void* d_ws, size_t ws_size,
                              hipStream_t stream)
{
    const float* x  = (const float*)d_in[0];
    const float* h0 = (const float*)d_in[1];
    const float* Wz = (const float*)d_in[2];
    const float* bz = (const float*)d_in[3];
    const float* Wh = (const float*)d_in[4];
    const float* bh = (const float*)d_in[5];
    float* out = (float*)d_out;

    // Workspace: wzb/whb 131K each | agg 512K  => ~0.8 MB.
    unsigned char* ws = (unsigned char*)d_ws;
    unsigned short* wzb = (unsigned short*)ws;   ws += (size_t)kH * kD * 2;
    unsigned short* whb = (unsigned short*)ws;   ws += (size_t)kH * kD * 2;
    unsigned long long* agg = (unsigned long long*)ws;

    constexpr int PREP_ITEMS = 2 * (kH * kD / 4)
                             + kNChain * kNT * TH * 8 / 16;   // 65,536
    prep<<<PREP_ITEMS / 256, 256, 0, stream>>>(
        Wz, Wh, wzb, whb, (float4*)agg);
    gemm_scan_fused<<<kNChain * kNT, 256, 0, stream>>>(
        x, wzb, whb, bz, bh, h0, agg, out);
}

// Round 7
// 132.760 us; speedup vs baseline: 1.2682x; 1.2682x over previous
//
#include <hip/hip_runtime.h>
#include <hip/hip_fp16.h>

// MinGRU single-pass fused pipeline, round 14. The acc-register invariant
// (all-resident one-tile-per-block => 64 acc f32/thread) is what killed
// every issue-early pipeline (r9 spill, r11 lost residency, r13 spill).
// This round breaks the invariant: TM=64, each block processes TWO 64-row
// tiles sequentially (tiles j and 32+j of its chain). acc halves to 32,
// freeing ~32 regs for the r9-style pipeline at FULL 4-blocks/CU residency:
//   LDS/block = Xs[64][64] bf16 (8K) + W dbuf 2x(Wz+Wh 8K each) (32K)
//             = 40960 B; 4 x 40960 = exactly 160 KB/CU.
//   Per K-iter: {issue next X reg-loads + next W DMA into other buf} ->
//   2 k-steps ds_read+MFMA -> barrier (drains VMEM issued a full phase
//   earlier) -> cvt+ds_write X -> lgkm barrier.
// Scan: 64 tiles/chain (1 MB mailbox). Round-1 lookback is seeded by
// carry = A*hs + B computed IN-REGISTER during round 0's publish phase
// (state after tile j), so round 1 only folds tiles j+1..31+j.
// Progress: all 1024 blocks resident; round-0 publish precedes any wait;
// round-1 waits only on peers' round-0/round-1 publishes => acyclic.
// XCD co-location (4 col-groups of one (b,j) share id%8) kept. Epilogue /
// batched lookback / nontemporal out structure kept, re-indexed for TM=64.

namespace {
constexpr int kB  = 8;
constexpr int kT  = 4096;
constexpr int kD  = 256;
constexpr int kH  = 256;

constexpr int TM  = 64;           // time rows per GEMM round
constexpr int TH  = 64;           // h cols per block (dual-W => 128 eff. N)
constexpr int BK  = 64;           // GEMM k tile
constexpr int kTilesPC = kT / TM;         // 64 tiles per chain
constexpr int kNChain  = kB * (kH / TH);  // 32 chains
constexpr int EPS = 66;           // epilogue LDS row stride (half)
} // namespace

typedef short s16x8 __attribute__((ext_vector_type(8)));
typedef short s16x4 __attribute__((ext_vector_type(4)));
typedef float f32x4 __attribute__((ext_vector_type(4)));

__device__ __forceinline__ short f2bf(float f) {
    union { float f; unsigned int u; } v; v.f = f;
    unsigned int r = v.u + 0x7fffu + ((v.u >> 16) & 1u);   // RNE
    return (short)(r >> 16);
}

// packed RNE f32x2 -> bf16x2 (low word = lo operand); same rounding as f2bf
__device__ __forceinline__ unsigned int cvt_pk_bf16(float lo, float hi) {
    unsigned int r;
    asm("v_cvt_pk_bf16_f32 %0, %1, %2" : "=v"(r) : "v"(lo), "v"(hi));
    return r;
}

__device__ __forceinline__ void load_lds16(const void* g, void* l) {
    __builtin_amdgcn_global_load_lds(
        (const __attribute__((address_space(1))) void*)g,
        (__attribute__((address_space(3))) void*)l, 16, 0, 0);
}

// ---------------------------------------------------------------------------
// Kernel 1 (tiny): fp32 -> bf16 for Wz, Wh; zero the 1 MB aggregate mailbox.
// ---------------------------------------------------------------------------
__global__ __launch_bounds__(256)
void prep(const float* __restrict__ Wz,
          const float* __restrict__ Wh,
          unsigned short* __restrict__ wzb,
          unsigned short* __restrict__ whb,
          float4* __restrict__ aggz)
{
    constexpr int W4 = kH * kD / 4;           // 16,384 each
    const int i = blockIdx.x * 256 + threadIdx.x;

    if (i >= 2 * W4) {                        // zero mailbox (65536 float4)
        float4 z; z.x = 0.f; z.y = 0.f; z.z = 0.f; z.w = 0.f;
        aggz[i - 2 * W4] = z;
        return;
    }
    const float* src; unsigned short* dst; int j;
    if (i < W4) { src = Wz; dst = wzb; j = i; }
    else        { src = Wh; dst = whb; j = i - W4; }
    const float4 v = ((const float4*)src)[j];
    s16x4 p;
    p[0] = f2bf(v.x); p[1] = f2bf(v.y); p[2] = f2bf(v.z); p[3] = f2bf(v.w);
    ((s16x4*)dst)[j] = p;
}

// ---------------------------------------------------------------------------
// Kernel 2: two sequential 64-row tiles per block; pipelined GEMM + sigmoid +
// aggregate + lookback (carry-seeded in round 1) + apply + out.
// Grid: 1024 blocks (XCD-swizzled 1-D), 4 waves, 4 blocks/CU (all resident).
// ---------------------------------------------------------------------------
__global__ __launch_bounds__(256, 4)
void gemm_scan_fused(const float* __restrict__ x,
                     const unsigned short* __restrict__ wzb,
                     const unsigned short* __restrict__ whb,
                     const float* __restrict__ bz,
                     const float* __restrict__ bh,
                     const float* __restrict__ h0,
                     unsigned long long* __restrict__ agg,  // [32][64][64]
                     float* __restrict__ out)
{
    // LDS: Xs[64][64] bf16 @0 (8K); W buf0 Wz@8192 Wh@16384; buf1 Wz@24576
    // Wh@32768; end 40960. Epilogue overlay (post K-loop): a_lds[64][66]
    // half @0 (8448), b_lds @8448 (ends 16896), sub_lds[4][64] float2
    // @16896, hs_lds[64] @18944. Total block LDS 40960 (4/CU = 160 KB).
    __shared__ __align__(16) unsigned char smem[40960];
    unsigned short* Xs = (unsigned short*)smem;      // [64][64]
    __half* a_lds   = (__half*)smem;                 // [64][EPS]
    __half* b_lds   = a_lds + 64 * EPS;
    float2* sub_lds = (float2*)(smem + 16896);       // [4][64]
    float*  hs_lds  = (float*)(smem + 18944);        // [64]

    const int tid  = threadIdx.x;
    const int lane = tid & 63;
    const int wv   = tid >> 6;
    const int ln15 = lane & 15;
    const int quad = lane >> 4;
    const int wr0  = (wv & 1) * 32;          // 2 row-groups of 32
    const int wc0  = (wv >> 1) * 32;         // 2 col-groups of 32

    // XCD co-location decode: the 4 col-groups of one (b,j) share id%8.
    // Bijective over 1024.
    const int id  = blockIdx.x;
    const int r8  = id & 7;
    const int q   = id >> 3;
    const int cg  = q & 3;                   // col-group 0..3
    const int idx = (q >> 2) * 8 + r8;       // 0..255
    const int b   = idx >> 5;
    const int j   = idx & 31;                // block index within chain
    const int chain = b * 4 + cg;            // 0..31
    const int col0  = cg * TH;

    // W DMA geometry: per matrix 8 segs of (8 rows x 8 16B slots); lane
    // covers row seg*8 + (lane>>3), LDS slot (lane&7); fetched global 16B
    // block = slot ^ srow. X reg-load: thread covers 2 16B-bf16 blocks
    // (bi = jj*256+tid): r = bi>>3, blk = bi&7; global = 8 fp32 at
    // (row0+r)*kD + blk*8 (wave-coalesced 8 rows x 256B).
    const int srow = lane >> 3;
    const int swslot = (lane & 7) ^ srow;
    const int xr   = tid >> 3;               // 0..31 (jj=1 adds 32)
    const int xblk = tid & 7;

    float carry = 0.f;                       // tid<64: state after tile j

    for (int rnd = 0; rnd < 2; ++rnd) {
        const int t    = j + rnd * 32;       // tile index 0..63
        const int row0 = b * kT + t * TM;

        f32x4 accZ[2][2] = {};
        f32x4 accU[2][2] = {};
        float4 xv0[2], xv1[2];

        // ---- prologue: X(0) regs + W(0) DMA into buf0; write X; sync
        #pragma unroll
        for (int jj = 0; jj < 2; ++jj) {
            const int r = jj * 32 + xr;
            const float* p = x + (size_t)(row0 + r) * kD + xblk * 8;
            xv0[jj] = *(const float4*)p;
            xv1[jj] = *(const float4*)(p + 4);
        }
        #pragma unroll
        for (int s2 = 0; s2 < 2; ++s2) {
            const int seg = wv * 2 + s2;
            const int m = seg * 8 + srow;
            load_lds16(wzb + (size_t)(col0 + m) * kD + swslot * 8,
                       smem + 8192 + seg * 1024);
            load_lds16(whb + (size_t)(col0 + m) * kD + swslot * 8,
                       smem + 16384 + seg * 1024);
        }
        #pragma unroll
        for (int jj = 0; jj < 2; ++jj) {
            const int r = jj * 32 + xr;
            union { unsigned int u[4]; s16x8 v; } pk;
            pk.u[0] = cvt_pk_bf16(xv0[jj].x, xv0[jj].y);
            pk.u[1] = cvt_pk_bf16(xv0[jj].z, xv0[jj].w);
            pk.u[2] = cvt_pk_bf16(xv1[jj].x, xv1[jj].y);
            pk.u[3] = cvt_pk_bf16(xv1[jj].z, xv1[jj].w);
            *(s16x8*)&Xs[r * 64 + ((xblk ^ (r & 7)) << 3)] = pk.v;
        }
        __syncthreads();   // drains W DMA (vmcnt) + X ds_writes (lgkm)

        // ---- pipelined K loop: 4 iters of BK=64
        #pragma unroll
        for (int k = 0; k < 4; ++k) {
            if (k < 3) {
                const int o = (k + 1) * BK;
                #pragma unroll
                for (int jj = 0; jj < 2; ++jj) {
                    const int r = jj * 32 + xr;
                    const float* p = x + (size_t)(row0 + r) * kD + o + xblk * 8;
                    xv0[jj] = *(const float4*)p;
                    xv1[jj] = *(const float4*)(p + 4);
                }
                unsigned char* wn = smem + 8192 + (((k + 1) & 1) ? 16384 : 0);
                #pragma unroll
                for (int s2 = 0; s2 < 2; ++s2) {
                    const int seg = wv * 2 + s2;
                    const int m = seg * 8 + srow;
                    load_lds16(wzb + (size_t)(col0 + m) * kD + o + swslot * 8,
                               wn + seg * 1024);
                    load_lds16(whb + (size_t)(col0 + m) * kD + o + swslot * 8,
                               wn + 8192 + seg * 1024);
                }
            }
            __builtin_amdgcn_sched_barrier(0);   // keep issues above compute

            const unsigned short* Wzc =
                (const unsigned short*)(smem + 8192 + ((k & 1) ? 16384 : 0));
            const unsigned short* Whc = Wzc + 4096;
            #pragma unroll
            for (int kk = 0; kk < BK; kk += 32) {
                const int bblk = (kk >> 3) + quad;
                s16x8 af[2], bzf[2], bhf[2];
                #pragma unroll
                for (int mt = 0; mt < 2; ++mt) {
                    const int r = wr0 + mt * 16 + ln15;
                    af[mt] = *(const s16x8*)&Xs[r * 64 + ((bblk ^ (r & 7)) << 3)];
                }
                #pragma unroll
                for (int nt = 0; nt < 2; ++nt) {
                    const int rw = wc0 + nt * 16 + ln15;
                    const int so = (bblk ^ (rw & 7)) << 3;
                    bzf[nt] = *(const s16x8*)&Wzc[rw * 64 + so];
                    bhf[nt] = *(const s16x8*)&Whc[rw * 64 + so];
                }
                __builtin_amdgcn_s_setprio(1);
                #pragma unroll
                for (int mt = 0; mt < 2; ++mt) {
                    #pragma unroll
                    for (int nt = 0; nt < 2; ++nt) {
                        accZ[mt][nt] = __builtin_amdgcn_mfma_f32_16x16x32_bf16(
                            af[mt], bzf[nt], accZ[mt][nt], 0, 0, 0);
                        accU[mt][nt] = __builtin_amdgcn_mfma_f32_16x16x32_bf16(
                            af[mt], bhf[nt], accU[mt][nt], 0, 0, 0);
                    }
                }
                __builtin_amdgcn_s_setprio(0);
            }
            __syncthreads();   // done reading Xs/W[k&1]; drains next VMEM

            if (k < 3) {
                #pragma unroll
                for (int jj = 0; jj < 2; ++jj) {
                    const int r = jj * 32 + xr;
                    union { unsigned int u[4]; s16x8 v; } pk;
                    pk.u[0] = cvt_pk_bf16(xv0[jj].x, xv0[jj].y);
                    pk.u[1] = cvt_pk_bf16(xv0[jj].z, xv0[jj].w);
                    pk.u[2] = cvt_pk_bf16(xv1[jj].x, xv1[jj].y);
                    pk.u[3] = cvt_pk_bf16(xv1[jj].z, xv1[jj].w);
                    *(s16x8*)&Xs[r * 64 + ((xblk ^ (r & 7)) << 3)] = pk.v;
                }
                __syncthreads();   // lgkm-only
            }
        }

        // ---- epilogue: sigmoid; a/bb -> LDS fp16 (C/D: col=ln15, row=quad*4+r)
        #pragma unroll
        for (int nt = 0; nt < 2; ++nt) {
            const int col = col0 + wc0 + nt * 16 + ln15;
            const int lc  = wc0 + nt * 16 + ln15;
            const float bzv = bz[col];
            const float bhv = bh[col];
            #pragma unroll
            for (int mt = 0; mt < 2; ++mt) {
                const int rb = wr0 + mt * 16 + quad * 4;
                #pragma unroll
                for (int r = 0; r < 4; ++r) {
                    const float z = accZ[mt][nt][r] + bzv;
                    const float g = 1.0f / (1.0f + __expf(-z));
                    const float u = accU[mt][nt][r] + bhv;
                    a_lds[(rb + r) * EPS + lc] = __float2half_rn(1.0f - g);
                    b_lds[(rb + r) * EPS + lc] = __float2half_rn(g * u);
                }
            }
        }
        __syncthreads();

        // ---- sub-chunk (16-row) affine summaries: thread (s,h)
        const int s = tid >> 6;
        const int h = tid & 63;
        {
            float A = 1.0f, Bv = 0.0f;
            #pragma unroll 8
            for (int r = s * 16; r < s * 16 + 16; ++r) {
                const float a  = __half2float(a_lds[r * EPS + h]);
                const float bb = __half2float(b_lds[r * EPS + h]);
                Bv = fmaf(a, Bv, bb);
                A *= a;
            }
            float2 o; o.x = A; o.y = Bv;
            sub_lds[s * 64 + h] = o;
        }
        __syncthreads();

        // ---- publish tile aggregate + lookback (one lane per h)
        if (tid < 64) {
            float A = 1.0f, Bv = 0.0f;
            #pragma unroll
            for (int s2 = 0; s2 < 4; ++s2) {
                const float2 g = sub_lds[s2 * 64 + tid];
                Bv = fmaf(g.x, Bv, g.y);
                A *= g.x;
            }
            union { float2 f; unsigned long long u; } pk;
            pk.f.x = A; pk.f.y = Bv;
            pk.u |= 1ull;                     // never 0 => unambiguous flag
            __hip_atomic_store(&agg[(size_t)(chain * kTilesPC + t) * 64 + tid],
                               pk.u, __ATOMIC_RELAXED, __HIP_MEMORY_SCOPE_AGENT);

            float hs;
            int p0;
            if (rnd == 0) { hs = h0[(size_t)b * kH + col0 + tid]; p0 = 0; }
            else          { hs = carry;                            p0 = j + 1; }
            for (; p0 < t; p0 += 8) {
                const int nb = (t - p0 < 8) ? (t - p0) : 8;
                unsigned long long u[8];
                #pragma unroll
                for (int q2 = 0; q2 < 8; ++q2)
                    if (q2 < nb)
                        u[q2] = __hip_atomic_load(
                            &agg[(size_t)(chain * kTilesPC + p0 + q2) * 64 + tid],
                            __ATOMIC_RELAXED, __HIP_MEMORY_SCOPE_AGENT);
                #pragma unroll
                for (int q2 = 0; q2 < 8; ++q2) {
                    if (q2 < nb) {
                        while (u[q2] == 0ull)
                            u[q2] = __hip_atomic_load(
                                &agg[(size_t)(chain * kTilesPC + p0 + q2) * 64 + tid],
                                __ATOMIC_RELAXED, __HIP_MEMORY_SCOPE_AGENT);
                        union { unsigned long long u; float2 f; } qk; qk.u = u[q2];
                        hs = fmaf(qk.f.x, hs, qk.f.y);
                    }
                }
            }
            hs_lds[tid] = hs;
            if (rnd == 0) carry = fmaf(A, hs, Bv);   // state after tile j
        }
        __syncthreads();

        // ---- apply recurrence: thread (s,h) does its 16 rows, writes out
        {
            float hv = hs_lds[h];
            #pragma unroll
            for (int s2 = 0; s2 < s; ++s2) {
                const float2 g = sub_lds[s2 * 64 + h];
                hv = fmaf(g.x, hv, g.y);
            }
            #pragma unroll 8
            for (int r = 0; r < 16; ++r) {
                const int lr = s * 16 + r;
                const float a  = __half2float(a_lds[lr * EPS + h]);
                const float bb = __half2float(b_lds[lr * EPS + h]);
                hv = fmaf(a, hv, bb);
                __builtin_nontemporal_store(
                    hv, &out[(size_t)(row0 + lr) * kH + col0 + h]);
            }
        }
        __syncthreads();   // LDS quiesced before next round's staging
    }
}

extern "C" void kernel_launch(void* const* d_in, const int* in_sizes, int n_in,
                              void* d_out, int out_size, void* d_ws, size_t ws_size,
                              hipStream_t stream)
{
    const float* x  = (const float*)d_in[0];
    const float* h0 = (const float*)d_in[1];
    const float* Wz = (const float*)d_in[2];
    const float* bz = (const float*)d_in[3];
    const float* Wh = (const float*)d_in[4];
    const float* bh = (const float*)d_in[5];
    float* out = (float*)d_out;

    // Workspace: wzb/whb 131K each | agg 1 MB  => ~1.3 MB.
    unsigned char* ws = (unsigned char*)d_ws;
    unsigned short* wzb = (unsigned short*)ws;   ws += (size_t)kH * kD * 2;
    unsigned short* whb = (unsigned short*)ws;   ws += (size_t)kH * kD * 2;
    unsigned long long* agg = (unsigned long long*)ws;

    constexpr int PREP_ITEMS = 2 * (kH * kD / 4)
                             + kNChain * kTilesPC * 64 * 8 / 16;   // 98,304
    prep<<<PREP_ITEMS / 256, 256, 0, stream>>>(
        Wz, Wh, wzb, whb, (float4*)agg);
    gemm_scan_fused<<<kNChain * 32, 256, 0, stream>>>(
        x, wzb, whb, bz, bh, h0, agg, out);
}

// Round 8
// 114.761 us; speedup vs baseline: 1.4672x; 1.1568x over previous
//
#include <hip/hip_runtime.h>
#include <hip/hip_fp16.h>

// MinGRU single-pass fused pipeline, round 15 = r10's proven skeleton with a
// fully double-buffered, register-free K pipeline. Every earlier issue-early
// attempt was confounded by a resource side effect (r9/r13 VGPR spill, r11
// occupancy loss, r12 coalescing loss, r14 scan duplication). The only way
// to deep-pipeline with ZERO extra registers and ZERO occupancy loss is
// bf16 X via global_load_lds -> resurrect r0's x->bf16 prologue (~8us,
// known) and run BK=32 with BOTH operands LDS-double-buffered:
//   X dbuf 2x8KB + W dbuf 2x8KB = 32KB <= 36KB epilogue overlay
//   => LDS 36096 unchanged => 4 blocks/CU, 16 waves/CU.
//   Per iter: {4 DMA instr/wave for tile k+1} -> 8 ds_read_b128 -> 16 MFMA
//   -> ONE barrier. The barrier's vmcnt(0) drains DMA issued a full compute
//   phase earlier (~600cy aged vs ~0 in r0/r10). No cvt in the loop.
// Swizzle for 64B rows (BK=32): row = 4 x 16B blocks; global block b of
// row r lives at LDS slot b ^ (r&3). DMA: lane covers row seg*16+(lane>>2),
// slot lane&3, fetches global block (lane&3)^((lane>>2)&3); dst linear.
// Epilogue / scan / batched lookback / apply / nontemporal out and the
// XCD co-location decode are byte-identical to r10.

namespace {
constexpr int kB  = 8;
constexpr int kT  = 4096;
constexpr int kD  = 256;
constexpr int kH  = 256;
constexpr int kBT = kB * kT;

constexpr int TM  = 128;          // time rows per block
constexpr int TH  = 64;           // h cols per block (dual-W => 128 eff. N)
constexpr int BK  = 32;           // GEMM k tile (8 iters)
constexpr int kNT = kT / TM;      // 32 time-tiles per chain
constexpr int kNChain = kB * (kH / TH);   // 32 chains
constexpr int EPS = 66;           // epilogue LDS row stride (half)
} // namespace

typedef short s16x8 __attribute__((ext_vector_type(8)));
typedef short s16x4 __attribute__((ext_vector_type(4)));
typedef float f32x4 __attribute__((ext_vector_type(4)));

__device__ __forceinline__ short f2bf(float f) {
    union { float f; unsigned int u; } v; v.f = f;
    unsigned int r = v.u + 0x7fffu + ((v.u >> 16) & 1u);   // RNE
    return (short)(r >> 16);
}

__device__ __forceinline__ void load_lds16(const void* g, void* l) {
    __builtin_amdgcn_global_load_lds(
        (const __attribute__((address_space(1))) void*)g,
        (__attribute__((address_space(3))) void*)l, 16, 0, 0);
}

// ---------------------------------------------------------------------------
// Kernel 1: fp32 -> bf16 for x, Wz, Wh; zero the 512 KB aggregate mailbox.
// (r0's prologue, verbatim: 8448 blocks, ~8us.)
// ---------------------------------------------------------------------------
__global__ __launch_bounds__(256)
void prologue(const float* __restrict__ x,
              const float* __restrict__ Wz,
              const float* __restrict__ Wh,
              unsigned short* __restrict__ xbg,
              unsigned short* __restrict__ wzb,
              unsigned short* __restrict__ whb,
              float4* __restrict__ aggz)
{
    constexpr int X4 = kBT * kD / 4;          // 2,097,152
    constexpr int W4 = kH  * kD / 4;          // 16,384 each
    const int i = blockIdx.x * 256 + threadIdx.x;

    if (i >= X4 + 2 * W4) {                   // zero mailbox
        float4 z; z.x = 0.f; z.y = 0.f; z.z = 0.f; z.w = 0.f;
        aggz[i - (X4 + 2 * W4)] = z;
        return;
    }
    const float* src; unsigned short* dst; int j;
    if (i < X4)           { src = x;  dst = xbg; j = i; }
    else if (i < X4 + W4) { src = Wz; dst = wzb; j = i - X4; }
    else                  { src = Wh; dst = whb; j = i - X4 - W4; }
    const float4 v = ((const float4*)src)[j];
    s16x4 p;
    p[0] = f2bf(v.x); p[1] = f2bf(v.y); p[2] = f2bf(v.z); p[3] = f2bf(v.w);
    ((s16x4*)dst)[j] = p;
}

// ---------------------------------------------------------------------------
// Kernel 2: fully double-buffered GEMM (1 barrier/iter, register-free
// staging) + sigmoid + block aggregate + lookback + apply + out.
// Grid: 1024 blocks (XCD-swizzled 1-D), 4 waves, 4 blocks/CU.
// ---------------------------------------------------------------------------
__global__ __launch_bounds__(256, 4)
void gemm_scan_fused(const unsigned short* __restrict__ xbg,
                     const unsigned short* __restrict__ wzb,
                     const unsigned short* __restrict__ whb,
                     const float* __restrict__ bz,
                     const float* __restrict__ bh,
                     const float* __restrict__ h0,
                     unsigned long long* __restrict__ agg,  // [32][32][64]
                     float* __restrict__ out)
{
    // LDS: X buf0 @0 (8K) | X buf1 @8192 | {Wz,Wh} buf0 @16384 (8K) |
    // {Wz,Wh} buf1 @24576 (8K) -> staging ends 32768. Epilogue overlay:
    // a_lds/b_lds [128][66] half @0 (33792); sub_lds[4][64] float2 @33792;
    // hs_lds[64] @35840. Total 36096 B => 4 blocks/CU.
    __shared__ __align__(16) unsigned char smem[36096];
    __half* a_lds   = (__half*)smem;                 // [128][EPS]
    __half* b_lds   = a_lds + 128 * EPS;
    float2* sub_lds = (float2*)(smem + 33792);       // [4][64]
    float*  hs_lds  = (float*)(smem + 35840);        // [64]

    const int tid  = threadIdx.x;
    const int lane = tid & 63;
    const int wv   = tid >> 6;
    const int ln15 = lane & 15;
    const int quad = lane >> 4;
    const int wr0  = (wv & 1) * 64;
    const int wc0  = (wv >> 1) * 32;

    // XCD co-location decode: the 4 col-groups of one (b,t) share id%8
    // (=> same XCD, shared X tile in that XCD's L2). Bijective over 1024.
    const int id  = blockIdx.x;
    const int r8  = id & 7;
    const int q   = id >> 3;
    const int cg  = q & 3;                   // col-group 0..3
    const int bt  = (q >> 2) * 8 + r8;       // 0..255
    const int b   = bt >> 5;
    const int t   = bt & 31;                 // time-tile in chain
    const int chain = b * 4 + cg;            // 0..31
    const int col0  = cg * TH;
    const int row0  = b * kT + t * TM;       // global BT row of tile top

    // DMA geometry (64B rows): per 1KB instr, 16 rows x 4 slots of 16B.
    // lane covers row seg*16 + (lane>>2), slot lane&3; fetched global 16B
    // block = slot ^ (row&3) = (lane&3) ^ ((lane>>2)&3). LDS dst linear.
    const int xrow   = lane >> 2;            // 0..15
    const int xfetch = (lane & 3) ^ (xrow & 3);

    f32x4 accZ[4][2] = {};
    f32x4 accU[4][2] = {};

    // ---- prologue: DMA X(0) + W(0) into buf0
    #pragma unroll
    for (int s2 = 0; s2 < 2; ++s2) {
        const int seg = wv * 2 + s2;                 // 0..7, rows seg*16..+16
        load_lds16(xbg + (size_t)(row0 + seg * 16 + xrow) * kD + xfetch * 8,
                   smem + seg * 1024);
    }
    load_lds16(wzb + (size_t)(col0 + wv * 16 + xrow) * kD + xfetch * 8,
               smem + 16384 + wv * 1024);
    load_lds16(whb + (size_t)(col0 + wv * 16 + xrow) * kD + xfetch * 8,
               smem + 20480 + wv * 1024);
    __syncthreads();   // drains tile-0 DMA (exposed once)

    // ---- K loop: 8 iters of BK=32, one barrier each, fully double-buffered
    #pragma unroll
    for (int k = 0; k < 8; ++k) {
        const int cur = k & 1;
        if (k < 7) {
            const int o  = (k + 1) * BK;
            const int nb = cur ^ 1;
            #pragma unroll
            for (int s2 = 0; s2 < 2; ++s2) {
                const int seg = wv * 2 + s2;
                load_lds16(
                    xbg + (size_t)(row0 + seg * 16 + xrow) * kD + o + xfetch * 8,
                    smem + nb * 8192 + seg * 1024);
            }
            load_lds16(wzb + (size_t)(col0 + wv * 16 + xrow) * kD + o + xfetch * 8,
                       smem + 16384 + nb * 8192 + wv * 1024);
            load_lds16(whb + (size_t)(col0 + wv * 16 + xrow) * kD + o + xfetch * 8,
                       smem + 16384 + nb * 8192 + 4096 + wv * 1024);
        }
        __builtin_amdgcn_sched_barrier(0);   // keep DMA issues above compute

        const unsigned short* Xc  = (const unsigned short*)(smem + cur * 8192);
        const unsigned short* Wzc = (const unsigned short*)(smem + 16384 + cur * 8192);
        const unsigned short* Whc = Wzc + 2048;      // +4096 B

        s16x8 af[4], bzf[2], bhf[2];
        #pragma unroll
        for (int mt = 0; mt < 4; ++mt) {
            const int r = wr0 + mt * 16 + ln15;
            af[mt] = *(const s16x8*)&Xc[r * 32 + ((quad ^ (r & 3)) << 3)];
        }
        #pragma unroll
        for (int nt = 0; nt < 2; ++nt) {
            const int rw = wc0 + nt * 16 + ln15;
            const int so = (quad ^ (rw & 3)) << 3;
            bzf[nt] = *(const s16x8*)&Wzc[rw * 32 + so];
            bhf[nt] = *(const s16x8*)&Whc[rw * 32 + so];
        }
        __builtin_amdgcn_s_setprio(1);
        #pragma unroll
        for (int mt = 0; mt < 4; ++mt) {
            #pragma unroll
            for (int nt = 0; nt < 2; ++nt) {
                accZ[mt][nt] = __builtin_amdgcn_mfma_f32_16x16x32_bf16(
                    af[mt], bzf[nt], accZ[mt][nt], 0, 0, 0);
                accU[mt][nt] = __builtin_amdgcn_mfma_f32_16x16x32_bf16(
                    af[mt], bhf[nt], accU[mt][nt], 0, 0, 0);
            }
        }
        __builtin_amdgcn_s_setprio(0);
        __syncthreads();   // waves done reading buf[cur]; drains DMA[k+1]
    }

    // ---- epilogue: sigmoid; a/bb -> LDS fp16 (C/D: col=ln15, row=quad*4+r)
    #pragma unroll
    for (int nt = 0; nt < 2; ++nt) {
        const int col = col0 + wc0 + nt * 16 + ln15;
        const int lc  = wc0 + nt * 16 + ln15;
        const float bzv = bz[col];
        const float bhv = bh[col];
        #pragma unroll
        for (int mt = 0; mt < 4; ++mt) {
            const int rb = wr0 + mt * 16 + quad * 4;
            #pragma unroll
            for (int r = 0; r < 4; ++r) {
                const float z = accZ[mt][nt][r] + bzv;
                const float g = 1.0f / (1.0f + __expf(-z));
                const float u = accU[mt][nt][r] + bhv;
                a_lds[(rb + r) * EPS + lc] = __float2half_rn(1.0f - g);
                b_lds[(rb + r) * EPS + lc] = __float2half_rn(g * u);
            }
        }
    }
    __syncthreads();

    // ---- sub-chunk (32-row) affine summaries: thread (s,h)
    const int s = tid >> 6;
    const int h = tid & 63;
    {
        float A = 1.0f, Bv = 0.0f;
        #pragma unroll 8
        for (int r = s * 32; r < s * 32 + 32; ++r) {
            const float a  = __half2float(a_lds[r * EPS + h]);
            const float bb = __half2float(b_lds[r * EPS + h]);
            Bv = fmaf(a, Bv, bb);
            A *= a;
        }
        float2 o; o.x = A; o.y = Bv;
        sub_lds[s * 64 + h] = o;
    }
    __syncthreads();

    // ---- publish block aggregate + batched lookback (one lane per h)
    if (tid < 64) {
        float A = 1.0f, Bv = 0.0f;
        #pragma unroll
        for (int s2 = 0; s2 < 4; ++s2) {
            const float2 g = sub_lds[s2 * 64 + tid];
            Bv = fmaf(g.x, Bv, g.y);
            A *= g.x;
        }
        union { float2 f; unsigned long long u; } pk;
        pk.f.x = A; pk.f.y = Bv;
        pk.u |= 1ull;                         // never 0 => unambiguous flag
        __hip_atomic_store(&agg[(size_t)(chain * kNT + t) * 64 + tid], pk.u,
                           __ATOMIC_RELAXED, __HIP_MEMORY_SCOPE_AGENT);

        // lookback over predecessors 0..t-1, 8 at a time (independent loads,
        // one L2/L3 latency per batch; fold strictly in order).
        float hs = h0[(size_t)b * kH + col0 + tid];
        for (int j0 = 0; j0 < t; j0 += 8) {
            const int nb = (t - j0 < 8) ? (t - j0) : 8;
            unsigned long long u[8];
            #pragma unroll
            for (int q2 = 0; q2 < 8; ++q2)
                if (q2 < nb)
                    u[q2] = __hip_atomic_load(
                        &agg[(size_t)(chain * kNT + j0 + q2) * 64 + tid],
                        __ATOMIC_RELAXED, __HIP_MEMORY_SCOPE_AGENT);
            #pragma unroll
            for (int q2 = 0; q2 < 8; ++q2) {
                if (q2 < nb) {
                    while (u[q2] == 0ull)
                        u[q2] = __hip_atomic_load(
                            &agg[(size_t)(chain * kNT + j0 + q2) * 64 + tid],
                            __ATOMIC_RELAXED, __HIP_MEMORY_SCOPE_AGENT);
                    union { unsigned long long u; float2 f; } qk; qk.u = u[q2];
                    hs = fmaf(qk.f.x, hs, qk.f.y);
                }
            }
        }
        hs_lds[tid] = hs;
    }
    __syncthreads();

    // ---- apply recurrence: thread (s,h) does its 32 rows, writes out
    {
        float hv = hs_lds[h];
        #pragma unroll
        for (int s2 = 0; s2 < s; ++s2) {
            const float2 g = sub_lds[s2 * 64 + h];
            hv = fmaf(g.x, hv, g.y);
        }
        #pragma unroll 8
        for (int r = 0; r < 32; ++r) {
            const int lr = s * 32 + r;
            const float a  = __half2float(a_lds[lr * EPS + h]);
            const float bb = __half2float(b_lds[lr * EPS + h]);
            hv = fmaf(a, hv, bb);
            __builtin_nontemporal_store(hv, &out[(size_t)(row0 + lr) * kH + col0 + h]);
        }
    }
}

extern "C" void kernel_launch(void* const* d_in, const int* in_sizes, int n_in,
                              void* d_out, int out_size, void* d_ws, size_t ws_size,
                              hipStream_t stream)
{
    const float* x  = (const float*)d_in[0];
    const float* h0 = (const float*)d_in[1];
    const float* Wz = (const float*)d_in[2];
    const float* bz = (const float*)d_in[3];
    const float* Wh = (const float*)d_in[4];
    const float* bh = (const float*)d_in[5];
    float* out = (float*)d_out;

    // Workspace: xb 16.78M | wzb/whb 131K each | agg 512K  => ~17.6 MB.
    unsigned char* ws = (unsigned char*)d_ws;
    unsigned short* xbg = (unsigned short*)ws;   ws += (size_t)kBT * kD * 2;
    unsigned short* wzb = (unsigned short*)ws;   ws += (size_t)kH * kD * 2;
    unsigned short* whb = (unsigned short*)ws;   ws += (size_t)kH * kD * 2;
    unsigned long long* agg = (unsigned long long*)ws;

    constexpr int PRO_ITEMS = kBT * kD / 4 + 2 * (kH * kD / 4)
                            + kNChain * kNT * TH * 8 / 16;   // 2,162,688
    prologue<<<PRO_ITEMS / 256, 256, 0, stream>>>(
        x, Wz, Wh, xbg, wzb, whb, (float4*)agg);
    gemm_scan_fused<<<kNChain * kNT, 256, 0, stream>>>(
        xbg, wzb, whb, bz, bh, h0, agg, out);
}